// Round 19
// baseline (301.546 us; speedup 1.0000x reference)
//
#include <hip/hip_runtime.h>
#include <hip/hip_bf16.h>
#include <math.h>

// H=W=56, C=128, WS=7, SS=3, NH=4, P=5, HD=32, NW=64, NTOK=49, N=54, B=64
// x rows: 3141 = 5 + 56*56; window-rows: 4096 = B*NW; tokens/window: 54

typedef __attribute__((ext_vector_type(8))) short bf16x8;
typedef __attribute__((ext_vector_type(4))) float f32x4;
typedef __attribute__((ext_vector_type(4))) unsigned short u16x4;

__device__ __forceinline__ float bf2f(unsigned short u) {
  union { unsigned int i; float f; } v; v.i = ((unsigned)u) << 16; return v.f;
}
__device__ __forceinline__ unsigned short f2b(float f) {
  __hip_bfloat16 b = __float2bfloat16(f);
  return *reinterpret_cast<unsigned short*>(&b);
}
__device__ __forceinline__ unsigned pkbf(float lo, float hi) {
  return ((unsigned)f2b(hi) << 16) | (unsigned)f2b(lo);
}
union Pk8 { bf16x8 v; unsigned w[4]; };

// ---------------------------------------------------------------------------
// Weight convert: wt[n][k] = bf16(w[k][n])
// ---------------------------------------------------------------------------
__global__ __launch_bounds__(256) void convert_wt(const float* __restrict__ w,
    __hip_bfloat16* __restrict__ wt, int K, int N)
{
  int idx = blockIdx.x * 256 + threadIdx.x;
  if (idx >= N * K) return;
  int n = idx / K, k = idx % K;
  wt[idx] = __float2bfloat16(w[(size_t)k * N + n]);
}

// ---------------------------------------------------------------------------
// Bias table gen (once): bias2[w][h][q][k] bf16, exp2-domain; k>=54 -> -inf
// ---------------------------------------------------------------------------
__global__ __launch_bounds__(256) void bias_gen(const float* __restrict__ rpb,
    __hip_bfloat16* __restrict__ tab)
{
  int w = blockIdx.x >> 2, h = blockIdx.x & 3;
  int wh = w >> 3, ww = w & 7;
  #pragma unroll
  for (int e = 0; e < 16; ++e) {
    int fi = e * 256 + threadIdx.x;
    int q = fi >> 6, k = fi & 63;
    float v;
    if (k >= 54) {
      v = -INFINITY;
    } else {
      v = 0.f;
      if (q >= 5 && q < 54 && k >= 5) {
        int tq = q - 5, tk = k - 5;
        int aq = tq / 7, bq_ = tq % 7, ak = tk / 7, bk = tk % 7;
        int dh = aq - ak + 6, dw = bq_ - bk + 6;
        v = rpb[(dh * 13 + dw) * 4 + h];
        int rq = wh * 7 + aq, cq = ww * 7 + bq_;
        int rk = wh * 7 + ak, ck = ww * 7 + bk;
        int zq = (rq < 49 ? 0 : (rq < 53 ? 1 : 2)) * 3 + (cq < 49 ? 0 : (cq < 53 ? 1 : 2));
        int zk = (rk < 49 ? 0 : (rk < 53 ? 1 : 2)) * 3 + (ck < 49 ? 0 : (ck < 53 ? 1 : 2));
        if (zq != zk) v += -100.f;
      }
      v *= 1.44269504088896f;
    }
    tab[((size_t)blockIdx.x << 12) + fi] = __float2bfloat16(v);
  }
}

// ---------------------------------------------------------------------------
// Phase-1 mega-kernel v8 (unchanged from round 18 — measured 183 µs, no
// spills): one block per window-row, 4 waves, 32 KB LDS, (256,4).
// ---------------------------------------------------------------------------
__global__ __launch_bounds__(256, 4) void phase1_fused(
    const float* __restrict__ x,
    const float* __restrict__ n1g, const float* __restrict__ n1b,
    const __hip_bfloat16* __restrict__ w_qkv, const float* __restrict__ qkv_b,
    const __hip_bfloat16* __restrict__ w_prj, const float* __restrict__ proj_b,
    const __hip_bfloat16* __restrict__ bias_tab,
    float* __restrict__ out, float* __restrict__ pbuf)
{
  __shared__ short lds[16384];   // 32 KB
  short* xn = lds;               // [64][128] until K build done; later ao
  const int tid = threadIdx.x;
  const int wv = tid >> 6, lane = tid & 63;
  const int c = lane & 15, g = lane >> 4;
  const int gi = blockIdx.x;
  const int w = gi & 63;
  short* Vb = lds + 8192 + wv * 2048;  // head wv V: [64 tok][32 d], swizzled

  // ================= LN1 + window gather (rows wv, wv+4, ...) =========
  {
    float g0 = n1g[lane], g1 = n1g[lane + 64];
    float b0 = n1b[lane], b1 = n1b[lane + 64];
    float v0a[14], v1a[14];
    #pragma unroll
    for (int rr = 0; rr < 14; ++rr) {
      int row = wv + rr * 4;
      int rowc = (row < 54) ? row : 0;
      int src;
      if (rowc < 5) {
        src = (gi & 63) * 3141 + rowc;
      } else {
        int b = gi >> 6, t = rowc - 5;
        int hp = (w >> 3) * 7 + t / 7 + 3; if (hp >= 56) hp -= 56;
        int wp = (w & 7) * 7 + t % 7 + 3;  if (wp >= 56) wp -= 56;
        src = b * 3141 + 5 + hp * 56 + wp;
      }
      const float* xr = x + (size_t)src * 128;
      v0a[rr] = xr[lane];
      v1a[rr] = xr[lane + 64];
    }
    #pragma unroll
    for (int rr = 0; rr < 14; ++rr) {
      int row = wv + rr * 4;
      if (row < 54) {
        float v0 = v0a[rr], v1 = v1a[rr];
        float s = v0 + v1, s2 = v0 * v0 + v1 * v1;
        #pragma unroll
        for (int off = 32; off > 0; off >>= 1) {
          s  += __shfl_xor(s,  off);
          s2 += __shfl_xor(s2, off);
        }
        float mu = s * (1.f / 128.f);
        float var = s2 * (1.f / 128.f) - mu * mu;
        float rs = rsqrtf(var + 1e-5f);
        float y0 = (v0 - mu) * rs * g0 + b0;
        float y1 = (v1 - mu) * rs * g1 + b1;
        int f = (row & 15) >> 1;
        int ca = lane, cb = lane + 64;
        xn[row * 128 + (((ca >> 3) ^ f) << 3) + (ca & 7)] = (short)f2b(y0);
        xn[row * 128 + (((cb >> 3) ^ f) << 3) + (cb & 7)] = (short)f2b(y1);
      }
    }
    for (int idx = tid; idx < 1280; idx += 256) xn[54 * 128 + idx] = 0;
  }
  __syncthreads();

  // ================= V tiles FIRST (lowest reg pressure) -> LDS =======
  #pragma unroll
  for (int tt = 0; tt < 2; ++tt) {
    int chb = tt * 16;
    int n0 = 256 + wv * 32 + chb;
    bf16x8 bfr[4];
    #pragma unroll
    for (int ks = 0; ks < 4; ++ks)
      bfr[ks] = *(const bf16x8*)(w_qkv + (size_t)(n0 + c) * 128 + ks * 32 + g * 8);
    f32x4 acct[4] = {};
    #pragma unroll
    for (int ks = 0; ks < 4; ++ks) {
      bf16x8 afr[4];
      #pragma unroll
      for (int mi = 0; mi < 4; ++mi) {
        int row = mi * 16 + c;
        afr[mi] = *(const bf16x8*)(xn + row * 128 +
                    (((ks * 4 + g) ^ ((row & 15) >> 1)) << 3));
      }
      __builtin_amdgcn_s_setprio(1);
      #pragma unroll
      for (int mi = 0; mi < 4; ++mi)
        acct[mi] = __builtin_amdgcn_mfma_f32_16x16x32_bf16(
            bfr[ks], afr[mi], acct[mi], 0, 0, 0);   // D[ch][tok]
      __builtin_amdgcn_s_setprio(0);
    }
    f32x4 bv = *(const f32x4*)(qkv_b + n0 + g * 4);
    int cpart = (chb >> 3) + (g >> 1);
    #pragma unroll
    for (int mi = 0; mi < 4; ++mi) {
      int tok = mi * 16 + c;
      int swz = (tok >> 3) & 3;
      u16x4 pw;
      #pragma unroll
      for (int r = 0; r < 4; ++r) pw[r] = f2b(acct[mi][r] + bv[r]);
      *(u16x4*)(Vb + tok * 32 + ((cpart ^ swz) << 3) + (g & 1) * 4) = pw;
    }
  }

  // ================= Q,K: channel-permuted tiles, incremental pack ====
  bf16x8 bq[4], kf[4];
  #pragma unroll
  for (int qk = 0; qk < 2; ++qk) {
    unsigned pkk[4][4];
    #pragma unroll
    for (int tt = 0; tt < 2; ++tt) {
      bf16x8 bfr[4];
      #pragma unroll
      for (int ks = 0; ks < 4; ++ks)
        bfr[ks] = *(const bf16x8*)(w_qkv +
            (size_t)(qk * 128 + wv * 32 + (c >> 2) * 8 + tt * 4 + (c & 3)) * 128 +
            ks * 32 + g * 8);
      f32x4 acct[4] = {};
      #pragma unroll
      for (int ks = 0; ks < 4; ++ks) {
        bf16x8 afr[4];
        #pragma unroll
        for (int mi = 0; mi < 4; ++mi) {
          int row = mi * 16 + c;
          afr[mi] = *(const bf16x8*)(xn + row * 128 +
                      (((ks * 4 + g) ^ ((row & 15) >> 1)) << 3));
        }
        __builtin_amdgcn_s_setprio(1);
        #pragma unroll
        for (int mi = 0; mi < 4; ++mi)
          acct[mi] = __builtin_amdgcn_mfma_f32_16x16x32_bf16(
              bfr[ks], afr[mi], acct[mi], 0, 0, 0);   // D[ch][tok]
        __builtin_amdgcn_s_setprio(0);
      }
      f32x4 bv = *(const f32x4*)(qkv_b + qk * 128 + wv * 32 + g * 8 + tt * 4);
      #pragma unroll
      for (int mi = 0; mi < 4; ++mi) {
        pkk[mi][2 * tt + 0] = pkbf(acct[mi][0] + bv[0], acct[mi][1] + bv[1]);
        pkk[mi][2 * tt + 1] = pkbf(acct[mi][2] + bv[2], acct[mi][3] + bv[3]);
      }
    }
    #pragma unroll
    for (int mi = 0; mi < 4; ++mi) {
      Pk8 u;
      u.w[0] = pkk[mi][0]; u.w[1] = pkk[mi][1];
      u.w[2] = pkk[mi][2]; u.w[3] = pkk[mi][3];
      if (qk) kf[mi] = u.v; else bq[mi] = u.v;
    }
  }

  // ================= QK^T straight from registers =====================
  f32x4 acc[4][4] = {};
  __builtin_amdgcn_s_setprio(1);
  #pragma unroll
  for (int mi = 0; mi < 4; ++mi)
    #pragma unroll
    for (int ni = 0; ni < 4; ++ni)
      acc[mi][ni] = __builtin_amdgcn_mfma_f32_16x16x32_bf16(
          kf[mi], bq[ni], acc[mi][ni], 0, 0, 0);   // D[k=mi*16+g*4+r][q=ni*16+c]
  __builtin_amdgcn_s_setprio(0);

  // ====== bias + softmax + early P-pack (acc dies here; paq = 32 regs) ====
  bf16x8 paq[2][4];
  {
    const unsigned short* bt = (const unsigned short*)bias_tab + ((size_t)(w * 4 + wv) << 12);
    const float SC = 0.17677669529663689f * 1.44269504088896f;
    #pragma unroll
    for (int ni = 0; ni < 4; ++ni) {
      u16x4 bb0 = *(const u16x4*)(bt + (ni * 16 + c) * 64 +  0 + g * 4);
      u16x4 bb1 = *(const u16x4*)(bt + (ni * 16 + c) * 64 + 16 + g * 4);
      u16x4 bb2 = *(const u16x4*)(bt + (ni * 16 + c) * 64 + 32 + g * 4);
      u16x4 bb3 = *(const u16x4*)(bt + (ni * 16 + c) * 64 + 48 + g * 4);
      #pragma unroll
      for (int r = 0; r < 4; ++r) {
        acc[0][ni][r] = acc[0][ni][r] * SC + bf2f(bb0[r]);
        acc[1][ni][r] = acc[1][ni][r] * SC + bf2f(bb1[r]);
        acc[2][ni][r] = acc[2][ni][r] * SC + bf2f(bb2[r]);
        acc[3][ni][r] = acc[3][ni][r] * SC + bf2f(bb3[r]);
      }
      float m2 = -3.0e38f;
      #pragma unroll
      for (int mi = 0; mi < 4; ++mi)
        #pragma unroll
        for (int r = 0; r < 4; ++r)
          m2 = fmaxf(m2, acc[mi][ni][r]);
      m2 = fmaxf(m2, __shfl_xor(m2, 16, 64));
      m2 = fmaxf(m2, __shfl_xor(m2, 32, 64));
      float sm = 0.f;
      #pragma unroll
      for (int mi = 0; mi < 4; ++mi)
        #pragma unroll
        for (int r = 0; r < 4; ++r) {
          float p = exp2f(acc[mi][ni][r] - m2);
          acc[mi][ni][r] = p;
          sm += p;
        }
      sm += __shfl_xor(sm, 16, 64);
      sm += __shfl_xor(sm, 32, 64);
      float inv = 1.0f / sm;
      Pk8 u0, u1;
      u0.w[0] = pkbf(acc[0][ni][0] * inv, acc[0][ni][1] * inv);
      u0.w[1] = pkbf(acc[0][ni][2] * inv, acc[0][ni][3] * inv);
      u0.w[2] = pkbf(acc[1][ni][0] * inv, acc[1][ni][1] * inv);
      u0.w[3] = pkbf(acc[1][ni][2] * inv, acc[1][ni][3] * inv);
      paq[0][ni] = u0.v;
      u1.w[0] = pkbf(acc[2][ni][0] * inv, acc[2][ni][1] * inv);
      u1.w[1] = pkbf(acc[2][ni][2] * inv, acc[2][ni][3] * inv);
      u1.w[2] = pkbf(acc[3][ni][0] * inv, acc[3][ni][1] * inv);
      u1.w[3] = pkbf(acc[3][ni][2] * inv, acc[3][ni][3] * inv);
      paq[1][ni] = u1.v;
    }
  }

  // ================= PV: paq (bf16) x V(LDS, pi-tokens) ===============
  f32x4 acc2[2][4] = {};
  #pragma unroll
  for (int ks = 0; ks < 2; ++ks) {
    bf16x8 vb[2];
    #pragma unroll
    for (int di = 0; di < 2; ++di) {
      #pragma unroll
      for (int j = 0; j < 8; ++j) {
        int ptok = (2 * ks + (j >> 2)) * 16 + g * 4 + (j & 3);
        int pswz = (2 * (j >> 2) + (g >> 1)) & 3;
        vb[di][j] = Vb[ptok * 32 + (((di * 2 + (c >> 3)) ^ pswz) << 3) + (c & 7)];
      }
    }
    __builtin_amdgcn_s_setprio(1);
    #pragma unroll
    for (int qi = 0; qi < 4; ++qi)
      #pragma unroll
      for (int di = 0; di < 2; ++di)
        acc2[di][qi] = __builtin_amdgcn_mfma_f32_16x16x32_bf16(
            vb[di], paq[ks][qi], acc2[di][qi], 0, 0, 0);   // D[d][q]
    __builtin_amdgcn_s_setprio(0);
  }

  __syncthreads();   // all waves done reading xn/V -> ao overlay safe
  // ao write: u16x4 of 4 consecutive channels per token
  #pragma unroll
  for (int di = 0; di < 2; ++di) {
    int chunk = wv * 4 + di * 2 + (g >> 1);
    #pragma unroll
    for (int qi = 0; qi < 4; ++qi) {
      int tok = qi * 16 + c;
      u16x4 pw;
      #pragma unroll
      for (int r = 0; r < 4; ++r) pw[r] = f2b(acc2[di][qi][r]);
      *(u16x4*)(xn + tok * 128 + ((chunk ^ (c >> 1)) << 3) + (g & 1) * 4) = pw;
    }
  }
  __syncthreads();

  // ================= proj GEMM + scatter epilogue =====================
  {
    f32x4 accp[4][2] = {};
    #pragma unroll
    for (int ks = 0; ks < 4; ++ks) {
      bf16x8 afp[4];
      #pragma unroll
      for (int mi = 0; mi < 4; ++mi) {
        int row = mi * 16 + c;
        afp[mi] = *(const bf16x8*)(xn + row * 128 +
                   (((ks * 4 + g) ^ ((row & 15) >> 1)) << 3));
      }
      bf16x8 wfp[2];
      #pragma unroll
      for (int ni = 0; ni < 2; ++ni)
        wfp[ni] = *(const bf16x8*)(w_prj +
            (size_t)(wv * 32 + ni * 16 + c) * 128 + ks * 32 + g * 8);
      #pragma unroll
      for (int mi = 0; mi < 4; ++mi)
        #pragma unroll
        for (int ni = 0; ni < 2; ++ni)
          accp[mi][ni] = __builtin_amdgcn_mfma_f32_16x16x32_bf16(
              afp[mi], wfp[ni], accp[mi][ni], 0, 0, 0);
    }
    float pb[2];
    pb[0] = proj_b[wv * 32 + c];
    pb[1] = proj_b[wv * 32 + 16 + c];
    #pragma unroll
    for (int mi = 0; mi < 4; ++mi) {
      #pragma unroll
      for (int r = 0; r < 4; ++r) {
        int tok = mi * 16 + g * 4 + r;
        if (tok < 54) {
          if (tok < 5) {
            #pragma unroll
            for (int ni = 0; ni < 2; ++ni) {
              int gcol = wv * 32 + ni * 16 + c;
              pbuf[((size_t)gi * 5 + tok) * 128 + gcol] = accp[mi][ni][r] + pb[ni];
            }
          } else {
            int b = gi >> 6, tt = tok - 5;
            int rr2 = (w >> 3) * 7 + tt / 7 + 3; if (rr2 >= 56) rr2 -= 56;
            int cc = (w & 7) * 7 + tt % 7 + 3;   if (cc >= 56) cc -= 56;
            size_t ob = ((size_t)b * 3141 + 5 + rr2 * 56 + cc) * 128;
            #pragma unroll
            for (int ni = 0; ni < 2; ++ni) {
              int gcol = wv * 32 + ni * 16 + c;
              out[ob + gcol] = x[ob + gcol] + accp[mi][ni][r] + pb[ni];
            }
          }
        }
      }
    }
  }
}

// ---------------------------------------------------------------------------
// Prompt mean over windows + residual
// ---------------------------------------------------------------------------
__global__ __launch_bounds__(128) void prompt_reduce(const float* __restrict__ x,
    const float* __restrict__ pbuf, float* __restrict__ out)
{
  int bp = blockIdx.x;
  int b = bp / 5, p = bp % 5;
  int c = threadIdx.x;
  float s = 0.f;
  for (int w = 0; w < 64; ++w)
    s += pbuf[((size_t)(w * 64 + b) * 5 + p) * 128 + c];
  size_t oidx = ((size_t)b * 3141 + p) * 128 + c;
  out[oidx] = x[oidx] + s * (1.f / 64.f);
}

// ---------------------------------------------------------------------------
// MLP helpers — 64-row blocks
// ---------------------------------------------------------------------------
__device__ __forceinline__ void mlp_fc1(const short* __restrict__ xn,
    short* __restrict__ dst, const __hip_bfloat16* __restrict__ w1t,
    const float* __restrict__ b1, int s, int wv, int c, int g)
{
  bf16x8 wf[4][2];
  #pragma unroll
  for (int ks = 0; ks < 4; ++ks)
    #pragma unroll
    for (int ni = 0; ni < 2; ++ni)
      wf[ks][ni] = *(const bf16x8*)(w1t +
          (size_t)(s * 128 + wv * 32 + ni * 16 + c) * 128 + ks * 32 + g * 8);
  f32x4 acc1[2][4] = {};
  #pragma unroll
  for (int ks = 0; ks < 4; ++ks) {
    bf16x8 af[4];
    #pragma unroll
    for (int mi = 0; mi < 4; ++mi) {
      int row = mi * 16 + c;
      af[mi] = *(const bf16x8*)(xn + row * 128 +
                                (((ks * 4 + g) ^ ((row & 15) >> 1)) << 3));
    }
    #pragma unroll
    for (int mi = 0; mi < 4; ++mi)
      #pragma unroll
      for (int ni = 0; ni < 2; ++ni)
        acc1[ni][mi] = __builtin_amdgcn_mfma_f32_16x16x32_bf16(
            wf[ks][ni], af[mi], acc1[ni][mi], 0, 0, 0);   // D[hcol][tok]
  }
  #pragma unroll
  for (int ni = 0; ni < 2; ++ni) {
    f32x4 b1v = *(const f32x4*)(b1 + s * 128 + wv * 32 + ni * 16 + g * 4);
    int chunk = wv * 4 + ni * 2 + (g >> 1);
    #pragma unroll
    for (int mi = 0; mi < 4; ++mi) {
      int tok = mi * 16 + c;
      u16x4 pw;
      #pragma unroll
      for (int r = 0; r < 4; ++r) {
        float t = acc1[ni][mi][r] + b1v[r];
        float u = t * (0.7978845608028654f + 0.0356774081f * t * t);
        float e = exp2f(-2.8853900817779268f * u);
        t = t * __builtin_amdgcn_rcpf(1.0f + e);
        pw[r] = f2b(t);
      }
      *(u16x4*)(dst + tok * 128 + ((chunk ^ (c >> 1)) << 3) + (g & 1) * 4) = pw;
    }
  }
}

__device__ __forceinline__ void mlp_fc2(const short* __restrict__ hsrc,
    const __hip_bfloat16* __restrict__ w2t, f32x4 (&acc2)[4][2],
    int s, int wv, int c, int g)
{
  bf16x8 wf[4][2];
  #pragma unroll
  for (int ks = 0; ks < 4; ++ks)
    #pragma unroll
    for (int ni = 0; ni < 2; ++ni)
      wf[ks][ni] = *(const bf16x8*)(w2t +
          (size_t)(wv * 32 + ni * 16 + c) * 512 + s * 128 + ks * 32 + g * 8);
  #pragma unroll
  for (int ks = 0; ks < 4; ++ks) {
    bf16x8 af[4];
    #pragma unroll
    for (int mi = 0; mi < 4; ++mi) {
      int row = mi * 16 + c;
      af[mi] = *(const bf16x8*)(hsrc + row * 128 +
                                (((ks * 4 + g) ^ ((row & 15) >> 1)) << 3));
    }
    #pragma unroll
    for (int mi = 0; mi < 4; ++mi)
      #pragma unroll
      for (int ni = 0; ni < 2; ++ni)
        acc2[mi][ni] = __builtin_amdgcn_mfma_f32_16x16x32_bf16(
            af[mi], wf[ks][ni], acc2[mi][ni], 0, 0, 0);
  }
}

// ---------------------------------------------------------------------------
// Fused MLP v5: 64-row blocks, SINGLE h buffer (32 KB LDS), (256,4) for
// 4 blocks/CU. Non-pipelined strip loop (fc1 -> bar -> fc2 -> bar); the
// lost intra-block overlap is covered by +33% inter-block TLP.
// ---------------------------------------------------------------------------
__global__ __launch_bounds__(256, 4) void mlp_fused(
    const float* __restrict__ xin,
    const float* __restrict__ gamma, const float* __restrict__ beta,
    const __hip_bfloat16* __restrict__ w1t, const float* __restrict__ b1,
    const __hip_bfloat16* __restrict__ w2t, const float* __restrict__ b2,
    float* __restrict__ outp)
{
  __shared__ short xn[8192];
  __shared__ short hb[8192];
  const int tid = threadIdx.x;
  const int wv = tid >> 6, lane = tid & 63;
  const int c = lane & 15, g = lane >> 4;
  const int r0 = blockIdx.x * 64;

  float v0a[16], v1a[16];
  #pragma unroll
  for (int rr = 0; rr < 16; ++rr) {
    int row = wv * 16 + rr;
    const float* xr = xin + (size_t)(r0 + row) * 128;
    v0a[rr] = xr[lane];
    v1a[rr] = xr[lane + 64];
  }
  #pragma unroll
  for (int rr = 0; rr < 16; ++rr) {
    int row = wv * 16 + rr;
    float v0 = v0a[rr], v1 = v1a[rr];
    float s = v0 + v1, s2 = v0 * v0 + v1 * v1;
    #pragma unroll
    for (int off = 32; off > 0; off >>= 1) {
      s  += __shfl_xor(s,  off);
      s2 += __shfl_xor(s2, off);
    }
    float mu = s * (1.f / 128.f);
    float var = s2 * (1.f / 128.f) - mu * mu;
    float rs = rsqrtf(var + 1e-5f);
    float y0 = (v0 - mu) * rs * gamma[lane]      + beta[lane];
    float y1 = (v1 - mu) * rs * gamma[lane + 64] + beta[lane + 64];
    int f = (row & 15) >> 1;
    int ca = lane, cb = lane + 64;
    xn[row * 128 + (((ca >> 3) ^ f) << 3) + (ca & 7)] = (short)f2b(y0);
    xn[row * 128 + (((cb >> 3) ^ f) << 3) + (cb & 7)] = (short)f2b(y1);
  }
  __syncthreads();

  f32x4 acc2[4][2] = {};
  #pragma unroll
  for (int s = 0; s < 4; ++s) {
    mlp_fc1(xn, hb, w1t, b1, s, wv, c, g);
    __syncthreads();
    mlp_fc2(hb, w2t, acc2, s, wv, c, g);
    if (s < 3) __syncthreads();
  }

  #pragma unroll
  for (int mi = 0; mi < 4; ++mi) {
    #pragma unroll
    for (int r = 0; r < 4; ++r) {
      int row = r0 + mi * 16 + g * 4 + r;
      #pragma unroll
      for (int ni = 0; ni < 2; ++ni) {
        int col = wv * 32 + ni * 16 + c;
        size_t o = (size_t)row * 128 + col;
        outp[o] = acc2[mi][ni][r] + b2[col] + xin[o];
      }
    }
  }
}

// ---------------------------------------------------------------------------
// Launch
// ---------------------------------------------------------------------------
extern "C" void kernel_launch(void* const* d_in, const int* in_sizes, int n_in,
                              void* d_out, int out_size, void* d_ws, size_t ws_size,
                              hipStream_t stream) {
  const float* x      = (const float*)d_in[0];
  const float* n1g    = (const float*)d_in[1];
  const float* n1b    = (const float*)d_in[2];
  const float* qkv_w  = (const float*)d_in[3];
  const float* qkv_b  = (const float*)d_in[4];
  const float* proj_w = (const float*)d_in[5];
  const float* proj_b = (const float*)d_in[6];
  const float* rpb    = (const float*)d_in[7];
  const float* n2g    = (const float*)d_in[8];
  const float* n2b    = (const float*)d_in[9];
  const float* fc1w   = (const float*)d_in[10];
  const float* fc1b   = (const float*)d_in[11];
  const float* fc2w   = (const float*)d_in[12];
  const float* fc2b   = (const float*)d_in[13];
  float* out = (float*)d_out;
  char* ws = (char*)d_ws;

  __hip_bfloat16* wbuf = (__hip_bfloat16*)ws;
  __hip_bfloat16* w_qkv = wbuf;                 // [384][128]
  __hip_bfloat16* w_prj = wbuf + 49152;         // [128][128]
  __hip_bfloat16* w_fc1 = wbuf + 65536;         // [512][128]
  __hip_bfloat16* w_fc2 = wbuf + 131072;        // [128][512]
  __hip_bfloat16* bias_tab = (__hip_bfloat16*)(ws + 393216);
  float* pbuf = (float*)(ws + 2490368);         // 4096*5*128 f32 = 10.5 MB

  hipLaunchKernelGGL(convert_wt, dim3(192), dim3(256), 0, stream, qkv_w, w_qkv, 128, 384);
  hipLaunchKernelGGL(convert_wt, dim3(64),  dim3(256), 0, stream, proj_w, w_prj, 128, 128);
  hipLaunchKernelGGL(convert_wt, dim3(256), dim3(256), 0, stream, fc1w,  w_fc1, 128, 512);
  hipLaunchKernelGGL(convert_wt, dim3(256), dim3(256), 0, stream, fc2w,  w_fc2, 512, 128);
  hipLaunchKernelGGL(bias_gen, dim3(256), dim3(256), 0, stream, rpb, bias_tab);

  // Phase 1: fully fused (no intermediate HBM traffic)
  hipLaunchKernelGGL(phase1_fused, dim3(4096), dim3(256), 0, stream,
                     x, n1g, n1b, w_qkv, qkv_b, w_prj, proj_b, bias_tab, out, pbuf);
  hipLaunchKernelGGL(prompt_reduce, dim3(320), dim3(128), 0, stream, x, pbuf, out);

  // Phase 2: fused MLP (in-place on out), 201024 = 3141*64 rows
  hipLaunchKernelGGL(mlp_fused, dim3(3141), dim3(256), 0, stream,
                     out, n2g, n2b, w_fc1, fc1b, w_fc2, fc2b, out);
  (void)in_sizes; (void)n_in; (void)out_size; (void)ws_size;
}

// Round 20
// 282.159 us; speedup vs baseline: 1.0687x; 1.0687x over previous
//
#include <hip/hip_runtime.h>
#include <hip/hip_bf16.h>
#include <math.h>

// H=W=56, C=128, WS=7, SS=3, NH=4, P=5, HD=32, NW=64, NTOK=49, N=54, B=64
// x rows: 3141 = 5 + 56*56; window-rows: 4096 = B*NW; tokens/window: 54

typedef __attribute__((ext_vector_type(8))) short bf16x8;
typedef __attribute__((ext_vector_type(4))) float f32x4;
typedef __attribute__((ext_vector_type(4))) unsigned short u16x4;

__device__ __forceinline__ float bf2f(unsigned short u) {
  union { unsigned int i; float f; } v; v.i = ((unsigned)u) << 16; return v.f;
}
__device__ __forceinline__ unsigned short f2b(float f) {
  __hip_bfloat16 b = __float2bfloat16(f);
  return *reinterpret_cast<unsigned short*>(&b);
}
__device__ __forceinline__ unsigned pkbf(float lo, float hi) {
  return ((unsigned)f2b(hi) << 16) | (unsigned)f2b(lo);
}
union Pk8 { bf16x8 v; unsigned w[4]; };

// ---------------------------------------------------------------------------
// Weight convert: wt[n][k] = bf16(w[k][n])
// ---------------------------------------------------------------------------
__global__ __launch_bounds__(256) void convert_wt(const float* __restrict__ w,
    __hip_bfloat16* __restrict__ wt, int K, int N)
{
  int idx = blockIdx.x * 256 + threadIdx.x;
  if (idx >= N * K) return;
  int n = idx / K, k = idx % K;
  wt[idx] = __float2bfloat16(w[(size_t)k * N + n]);
}

// ---------------------------------------------------------------------------
// Bias table gen (once): bias2[w][h][q][k] bf16, exp2-domain; k>=54 -> -inf
// ---------------------------------------------------------------------------
__global__ __launch_bounds__(256) void bias_gen(const float* __restrict__ rpb,
    __hip_bfloat16* __restrict__ tab)
{
  int w = blockIdx.x >> 2, h = blockIdx.x & 3;
  int wh = w >> 3, ww = w & 7;
  #pragma unroll
  for (int e = 0; e < 16; ++e) {
    int fi = e * 256 + threadIdx.x;
    int q = fi >> 6, k = fi & 63;
    float v;
    if (k >= 54) {
      v = -INFINITY;
    } else {
      v = 0.f;
      if (q >= 5 && q < 54 && k >= 5) {
        int tq = q - 5, tk = k - 5;
        int aq = tq / 7, bq_ = tq % 7, ak = tk / 7, bk = tk % 7;
        int dh = aq - ak + 6, dw = bq_ - bk + 6;
        v = rpb[(dh * 13 + dw) * 4 + h];
        int rq = wh * 7 + aq, cq = ww * 7 + bq_;
        int rk = wh * 7 + ak, ck = ww * 7 + bk;
        int zq = (rq < 49 ? 0 : (rq < 53 ? 1 : 2)) * 3 + (cq < 49 ? 0 : (cq < 53 ? 1 : 2));
        int zk = (rk < 49 ? 0 : (rk < 53 ? 1 : 2)) * 3 + (ck < 49 ? 0 : (ck < 53 ? 1 : 2));
        if (zq != zk) v += -100.f;
      }
      v *= 1.44269504088896f;
    }
    tab[((size_t)blockIdx.x << 12) + fi] = __float2bfloat16(v);
  }
}

// ---------------------------------------------------------------------------
// Phase-1 mega-kernel v8 (round-18 best: 183 µs, no spills): one block per
// window-row, 4 waves, 32 KB LDS, (256,4). Incremental Q/K pack + early
// P-pack keep all stage peaks < 128 regs.
// ---------------------------------------------------------------------------
__global__ __launch_bounds__(256, 4) void phase1_fused(
    const float* __restrict__ x,
    const float* __restrict__ n1g, const float* __restrict__ n1b,
    const __hip_bfloat16* __restrict__ w_qkv, const float* __restrict__ qkv_b,
    const __hip_bfloat16* __restrict__ w_prj, const float* __restrict__ proj_b,
    const __hip_bfloat16* __restrict__ bias_tab,
    float* __restrict__ out, float* __restrict__ pbuf)
{
  __shared__ short lds[16384];   // 32 KB
  short* xn = lds;               // [64][128] until K build done; later ao
  const int tid = threadIdx.x;
  const int wv = tid >> 6, lane = tid & 63;
  const int c = lane & 15, g = lane >> 4;
  const int gi = blockIdx.x;
  const int w = gi & 63;
  short* Vb = lds + 8192 + wv * 2048;  // head wv V: [64 tok][32 d], swizzled

  // ================= LN1 + window gather (rows wv, wv+4, ...) =========
  {
    float g0 = n1g[lane], g1 = n1g[lane + 64];
    float b0 = n1b[lane], b1 = n1b[lane + 64];
    float v0a[14], v1a[14];
    #pragma unroll
    for (int rr = 0; rr < 14; ++rr) {
      int row = wv + rr * 4;
      int rowc = (row < 54) ? row : 0;
      int src;
      if (rowc < 5) {
        src = (gi & 63) * 3141 + rowc;
      } else {
        int b = gi >> 6, t = rowc - 5;
        int hp = (w >> 3) * 7 + t / 7 + 3; if (hp >= 56) hp -= 56;
        int wp = (w & 7) * 7 + t % 7 + 3;  if (wp >= 56) wp -= 56;
        src = b * 3141 + 5 + hp * 56 + wp;
      }
      const float* xr = x + (size_t)src * 128;
      v0a[rr] = xr[lane];
      v1a[rr] = xr[lane + 64];
    }
    #pragma unroll
    for (int rr = 0; rr < 14; ++rr) {
      int row = wv + rr * 4;
      if (row < 54) {
        float v0 = v0a[rr], v1 = v1a[rr];
        float s = v0 + v1, s2 = v0 * v0 + v1 * v1;
        #pragma unroll
        for (int off = 32; off > 0; off >>= 1) {
          s  += __shfl_xor(s,  off);
          s2 += __shfl_xor(s2, off);
        }
        float mu = s * (1.f / 128.f);
        float var = s2 * (1.f / 128.f) - mu * mu;
        float rs = rsqrtf(var + 1e-5f);
        float y0 = (v0 - mu) * rs * g0 + b0;
        float y1 = (v1 - mu) * rs * g1 + b1;
        int f = (row & 15) >> 1;
        int ca = lane, cb = lane + 64;
        xn[row * 128 + (((ca >> 3) ^ f) << 3) + (ca & 7)] = (short)f2b(y0);
        xn[row * 128 + (((cb >> 3) ^ f) << 3) + (cb & 7)] = (short)f2b(y1);
      }
    }
    for (int idx = tid; idx < 1280; idx += 256) xn[54 * 128 + idx] = 0;
  }
  __syncthreads();

  // ================= V tiles FIRST (lowest reg pressure) -> LDS =======
  #pragma unroll
  for (int tt = 0; tt < 2; ++tt) {
    int chb = tt * 16;
    int n0 = 256 + wv * 32 + chb;
    bf16x8 bfr[4];
    #pragma unroll
    for (int ks = 0; ks < 4; ++ks)
      bfr[ks] = *(const bf16x8*)(w_qkv + (size_t)(n0 + c) * 128 + ks * 32 + g * 8);
    f32x4 acct[4] = {};
    #pragma unroll
    for (int ks = 0; ks < 4; ++ks) {
      bf16x8 afr[4];
      #pragma unroll
      for (int mi = 0; mi < 4; ++mi) {
        int row = mi * 16 + c;
        afr[mi] = *(const bf16x8*)(xn + row * 128 +
                    (((ks * 4 + g) ^ ((row & 15) >> 1)) << 3));
      }
      __builtin_amdgcn_s_setprio(1);
      #pragma unroll
      for (int mi = 0; mi < 4; ++mi)
        acct[mi] = __builtin_amdgcn_mfma_f32_16x16x32_bf16(
            bfr[ks], afr[mi], acct[mi], 0, 0, 0);   // D[ch][tok]
      __builtin_amdgcn_s_setprio(0);
    }
    f32x4 bv = *(const f32x4*)(qkv_b + n0 + g * 4);
    int cpart = (chb >> 3) + (g >> 1);
    #pragma unroll
    for (int mi = 0; mi < 4; ++mi) {
      int tok = mi * 16 + c;
      int swz = (tok >> 3) & 3;
      u16x4 pw;
      #pragma unroll
      for (int r = 0; r < 4; ++r) pw[r] = f2b(acct[mi][r] + bv[r]);
      *(u16x4*)(Vb + tok * 32 + ((cpart ^ swz) << 3) + (g & 1) * 4) = pw;
    }
  }

  // ================= Q,K: channel-permuted tiles, incremental pack ====
  bf16x8 bq[4], kf[4];
  #pragma unroll
  for (int qk = 0; qk < 2; ++qk) {
    unsigned pkk[4][4];
    #pragma unroll
    for (int tt = 0; tt < 2; ++tt) {
      bf16x8 bfr[4];
      #pragma unroll
      for (int ks = 0; ks < 4; ++ks)
        bfr[ks] = *(const bf16x8*)(w_qkv +
            (size_t)(qk * 128 + wv * 32 + (c >> 2) * 8 + tt * 4 + (c & 3)) * 128 +
            ks * 32 + g * 8);
      f32x4 acct[4] = {};
      #pragma unroll
      for (int ks = 0; ks < 4; ++ks) {
        bf16x8 afr[4];
        #pragma unroll
        for (int mi = 0; mi < 4; ++mi) {
          int row = mi * 16 + c;
          afr[mi] = *(const bf16x8*)(xn + row * 128 +
                      (((ks * 4 + g) ^ ((row & 15) >> 1)) << 3));
        }
        __builtin_amdgcn_s_setprio(1);
        #pragma unroll
        for (int mi = 0; mi < 4; ++mi)
          acct[mi] = __builtin_amdgcn_mfma_f32_16x16x32_bf16(
              bfr[ks], afr[mi], acct[mi], 0, 0, 0);   // D[ch][tok]
        __builtin_amdgcn_s_setprio(0);
      }
      f32x4 bv = *(const f32x4*)(qkv_b + qk * 128 + wv * 32 + g * 8 + tt * 4);
      #pragma unroll
      for (int mi = 0; mi < 4; ++mi) {
        pkk[mi][2 * tt + 0] = pkbf(acct[mi][0] + bv[0], acct[mi][1] + bv[1]);
        pkk[mi][2 * tt + 1] = pkbf(acct[mi][2] + bv[2], acct[mi][3] + bv[3]);
      }
    }
    #pragma unroll
    for (int mi = 0; mi < 4; ++mi) {
      Pk8 u;
      u.w[0] = pkk[mi][0]; u.w[1] = pkk[mi][1];
      u.w[2] = pkk[mi][2]; u.w[3] = pkk[mi][3];
      if (qk) kf[mi] = u.v; else bq[mi] = u.v;
    }
  }

  // ================= QK^T straight from registers =====================
  f32x4 acc[4][4] = {};
  __builtin_amdgcn_s_setprio(1);
  #pragma unroll
  for (int mi = 0; mi < 4; ++mi)
    #pragma unroll
    for (int ni = 0; ni < 4; ++ni)
      acc[mi][ni] = __builtin_amdgcn_mfma_f32_16x16x32_bf16(
          kf[mi], bq[ni], acc[mi][ni], 0, 0, 0);   // D[k=mi*16+g*4+r][q=ni*16+c]
  __builtin_amdgcn_s_setprio(0);

  // ====== bias + softmax + early P-pack (acc dies here; paq = 32 regs) ====
  bf16x8 paq[2][4];
  {
    const unsigned short* bt = (const unsigned short*)bias_tab + ((size_t)(w * 4 + wv) << 12);
    const float SC = 0.17677669529663689f * 1.44269504088896f;
    #pragma unroll
    for (int ni = 0; ni < 4; ++ni) {
      u16x4 bb0 = *(const u16x4*)(bt + (ni * 16 + c) * 64 +  0 + g * 4);
      u16x4 bb1 = *(const u16x4*)(bt + (ni * 16 + c) * 64 + 16 + g * 4);
      u16x4 bb2 = *(const u16x4*)(bt + (ni * 16 + c) * 64 + 32 + g * 4);
      u16x4 bb3 = *(const u16x4*)(bt + (ni * 16 + c) * 64 + 48 + g * 4);
      #pragma unroll
      for (int r = 0; r < 4; ++r) {
        acc[0][ni][r] = acc[0][ni][r] * SC + bf2f(bb0[r]);
        acc[1][ni][r] = acc[1][ni][r] * SC + bf2f(bb1[r]);
        acc[2][ni][r] = acc[2][ni][r] * SC + bf2f(bb2[r]);
        acc[3][ni][r] = acc[3][ni][r] * SC + bf2f(bb3[r]);
      }
      float m2 = -3.0e38f;
      #pragma unroll
      for (int mi = 0; mi < 4; ++mi)
        #pragma unroll
        for (int r = 0; r < 4; ++r)
          m2 = fmaxf(m2, acc[mi][ni][r]);
      m2 = fmaxf(m2, __shfl_xor(m2, 16, 64));
      m2 = fmaxf(m2, __shfl_xor(m2, 32, 64));
      float sm = 0.f;
      #pragma unroll
      for (int mi = 0; mi < 4; ++mi)
        #pragma unroll
        for (int r = 0; r < 4; ++r) {
          float p = exp2f(acc[mi][ni][r] - m2);
          acc[mi][ni][r] = p;
          sm += p;
        }
      sm += __shfl_xor(sm, 16, 64);
      sm += __shfl_xor(sm, 32, 64);
      float inv = 1.0f / sm;
      Pk8 u0, u1;
      u0.w[0] = pkbf(acc[0][ni][0] * inv, acc[0][ni][1] * inv);
      u0.w[1] = pkbf(acc[0][ni][2] * inv, acc[0][ni][3] * inv);
      u0.w[2] = pkbf(acc[1][ni][0] * inv, acc[1][ni][1] * inv);
      u0.w[3] = pkbf(acc[1][ni][2] * inv, acc[1][ni][3] * inv);
      paq[0][ni] = u0.v;
      u1.w[0] = pkbf(acc[2][ni][0] * inv, acc[2][ni][1] * inv);
      u1.w[1] = pkbf(acc[2][ni][2] * inv, acc[2][ni][3] * inv);
      u1.w[2] = pkbf(acc[3][ni][0] * inv, acc[3][ni][1] * inv);
      u1.w[3] = pkbf(acc[3][ni][2] * inv, acc[3][ni][3] * inv);
      paq[1][ni] = u1.v;
    }
  }

  // ================= PV: paq (bf16) x V(LDS, pi-tokens) ===============
  f32x4 acc2[2][4] = {};
  #pragma unroll
  for (int ks = 0; ks < 2; ++ks) {
    bf16x8 vb[2];
    #pragma unroll
    for (int di = 0; di < 2; ++di) {
      #pragma unroll
      for (int j = 0; j < 8; ++j) {
        int ptok = (2 * ks + (j >> 2)) * 16 + g * 4 + (j & 3);
        int pswz = (2 * (j >> 2) + (g >> 1)) & 3;
        vb[di][j] = Vb[ptok * 32 + (((di * 2 + (c >> 3)) ^ pswz) << 3) + (c & 7)];
      }
    }
    __builtin_amdgcn_s_setprio(1);
    #pragma unroll
    for (int qi = 0; qi < 4; ++qi)
      #pragma unroll
      for (int di = 0; di < 2; ++di)
        acc2[di][qi] = __builtin_amdgcn_mfma_f32_16x16x32_bf16(
            vb[di], paq[ks][qi], acc2[di][qi], 0, 0, 0);   // D[d][q]
    __builtin_amdgcn_s_setprio(0);
  }

  __syncthreads();   // all waves done reading xn/V -> ao overlay safe
  // ao write: u16x4 of 4 consecutive channels per token
  #pragma unroll
  for (int di = 0; di < 2; ++di) {
    int chunk = wv * 4 + di * 2 + (g >> 1);
    #pragma unroll
    for (int qi = 0; qi < 4; ++qi) {
      int tok = qi * 16 + c;
      u16x4 pw;
      #pragma unroll
      for (int r = 0; r < 4; ++r) pw[r] = f2b(acc2[di][qi][r]);
      *(u16x4*)(xn + tok * 128 + ((chunk ^ (c >> 1)) << 3) + (g & 1) * 4) = pw;
    }
  }
  __syncthreads();

  // ================= proj GEMM + scatter epilogue =====================
  {
    f32x4 accp[4][2] = {};
    #pragma unroll
    for (int ks = 0; ks < 4; ++ks) {
      bf16x8 afp[4];
      #pragma unroll
      for (int mi = 0; mi < 4; ++mi) {
        int row = mi * 16 + c;
        afp[mi] = *(const bf16x8*)(xn + row * 128 +
                   (((ks * 4 + g) ^ ((row & 15) >> 1)) << 3));
      }
      bf16x8 wfp[2];
      #pragma unroll
      for (int ni = 0; ni < 2; ++ni)
        wfp[ni] = *(const bf16x8*)(w_prj +
            (size_t)(wv * 32 + ni * 16 + c) * 128 + ks * 32 + g * 8);
      #pragma unroll
      for (int mi = 0; mi < 4; ++mi)
        #pragma unroll
        for (int ni = 0; ni < 2; ++ni)
          accp[mi][ni] = __builtin_amdgcn_mfma_f32_16x16x32_bf16(
              afp[mi], wfp[ni], accp[mi][ni], 0, 0, 0);
    }
    float pb[2];
    pb[0] = proj_b[wv * 32 + c];
    pb[1] = proj_b[wv * 32 + 16 + c];
    #pragma unroll
    for (int mi = 0; mi < 4; ++mi) {
      #pragma unroll
      for (int r = 0; r < 4; ++r) {
        int tok = mi * 16 + g * 4 + r;
        if (tok < 54) {
          if (tok < 5) {
            #pragma unroll
            for (int ni = 0; ni < 2; ++ni) {
              int gcol = wv * 32 + ni * 16 + c;
              pbuf[((size_t)gi * 5 + tok) * 128 + gcol] = accp[mi][ni][r] + pb[ni];
            }
          } else {
            int b = gi >> 6, tt = tok - 5;
            int rr2 = (w >> 3) * 7 + tt / 7 + 3; if (rr2 >= 56) rr2 -= 56;
            int cc = (w & 7) * 7 + tt % 7 + 3;   if (cc >= 56) cc -= 56;
            size_t ob = ((size_t)b * 3141 + 5 + rr2 * 56 + cc) * 128;
            #pragma unroll
            for (int ni = 0; ni < 2; ++ni) {
              int gcol = wv * 32 + ni * 16 + c;
              out[ob + gcol] = x[ob + gcol] + accp[mi][ni][r] + pb[ni];
            }
          }
        }
      }
    }
  }
}

// ---------------------------------------------------------------------------
// Prompt mean over windows + residual
// ---------------------------------------------------------------------------
__global__ __launch_bounds__(128) void prompt_reduce(const float* __restrict__ x,
    const float* __restrict__ pbuf, float* __restrict__ out)
{
  int bp = blockIdx.x;
  int b = bp / 5, p = bp % 5;
  int c = threadIdx.x;
  float s = 0.f;
  for (int w = 0; w < 64; ++w)
    s += pbuf[((size_t)(w * 64 + b) * 5 + p) * 128 + c];
  size_t oidx = ((size_t)b * 3141 + p) * 128 + c;
  out[oidx] = x[oidx] + s * (1.f / 64.f);
}

// ---------------------------------------------------------------------------
// MLP helpers — 64-row blocks (round-13 version, measured ~95 µs)
// ---------------------------------------------------------------------------
__device__ __forceinline__ void mlp_fc1(const short* __restrict__ xn,
    short* __restrict__ dst, const __hip_bfloat16* __restrict__ w1t,
    const float* __restrict__ b1, int s, int wv, int c, int g)
{
  bf16x8 wf[4][2];
  #pragma unroll
  for (int ks = 0; ks < 4; ++ks)
    #pragma unroll
    for (int ni = 0; ni < 2; ++ni)
      wf[ks][ni] = *(const bf16x8*)(w1t +
          (size_t)(s * 128 + wv * 32 + ni * 16 + c) * 128 + ks * 32 + g * 8);
  f32x4 acc1[2][4] = {};
  #pragma unroll
  for (int ks = 0; ks < 4; ++ks) {
    bf16x8 af[4];
    #pragma unroll
    for (int mi = 0; mi < 4; ++mi) {
      int row = mi * 16 + c;
      af[mi] = *(const bf16x8*)(xn + row * 128 +
                                (((ks * 4 + g) ^ ((row & 15) >> 1)) << 3));
    }
    #pragma unroll
    for (int mi = 0; mi < 4; ++mi)
      #pragma unroll
      for (int ni = 0; ni < 2; ++ni)
        acc1[ni][mi] = __builtin_amdgcn_mfma_f32_16x16x32_bf16(
            wf[ks][ni], af[mi], acc1[ni][mi], 0, 0, 0);   // D[hcol][tok]
  }
  #pragma unroll
  for (int ni = 0; ni < 2; ++ni) {
    f32x4 b1v = *(const f32x4*)(b1 + s * 128 + wv * 32 + ni * 16 + g * 4);
    int chunk = wv * 4 + ni * 2 + (g >> 1);
    #pragma unroll
    for (int mi = 0; mi < 4; ++mi) {
      int tok = mi * 16 + c;
      u16x4 pw;
      #pragma unroll
      for (int r = 0; r < 4; ++r) {
        float t = acc1[ni][mi][r] + b1v[r];
        float u = t * (0.7978845608028654f + 0.0356774081f * t * t);
        float e = exp2f(-2.8853900817779268f * u);
        t = t * __builtin_amdgcn_rcpf(1.0f + e);
        pw[r] = f2b(t);
      }
      *(u16x4*)(dst + tok * 128 + ((chunk ^ (c >> 1)) << 3) + (g & 1) * 4) = pw;
    }
  }
}

__device__ __forceinline__ void mlp_fc2(const short* __restrict__ hsrc,
    const __hip_bfloat16* __restrict__ w2t, f32x4 (&acc2)[4][2],
    int s, int wv, int c, int g)
{
  bf16x8 wf[4][2];
  #pragma unroll
  for (int ks = 0; ks < 4; ++ks)
    #pragma unroll
    for (int ni = 0; ni < 2; ++ni)
      wf[ks][ni] = *(const bf16x8*)(w2t +
          (size_t)(wv * 32 + ni * 16 + c) * 512 + s * 128 + ks * 32 + g * 8);
  #pragma unroll
  for (int ks = 0; ks < 4; ++ks) {
    bf16x8 af[4];
    #pragma unroll
    for (int mi = 0; mi < 4; ++mi) {
      int row = mi * 16 + c;
      af[mi] = *(const bf16x8*)(hsrc + row * 128 +
                                (((ks * 4 + g) ^ ((row & 15) >> 1)) << 3));
    }
    #pragma unroll
    for (int mi = 0; mi < 4; ++mi)
      #pragma unroll
      for (int ni = 0; ni < 2; ++ni)
        acc2[mi][ni] = __builtin_amdgcn_mfma_f32_16x16x32_bf16(
            af[mi], wf[ks][ni], acc2[mi][ni], 0, 0, 0);
  }
}

// ---------------------------------------------------------------------------
// Fused MLP (round-13 version): 64-row blocks, pipelined strips, dbuf h,
// 48KB LDS, packed u16x4 h-writes, (256,3).
// ---------------------------------------------------------------------------
__global__ __launch_bounds__(256, 3) void mlp_fused(
    const float* __restrict__ xin,
    const float* __restrict__ gamma, const float* __restrict__ beta,
    const __hip_bfloat16* __restrict__ w1t, const float* __restrict__ b1,
    const __hip_bfloat16* __restrict__ w2t, const float* __restrict__ b2,
    float* __restrict__ outp)
{
  __shared__ short xn[8192];
  __shared__ short hb[2][8192];
  const int tid = threadIdx.x;
  const int wv = tid >> 6, lane = tid & 63;
  const int c = lane & 15, g = lane >> 4;
  const int r0 = blockIdx.x * 64;

  float v0a[16], v1a[16];
  #pragma unroll
  for (int rr = 0; rr < 16; ++rr) {
    int row = wv * 16 + rr;
    const float* xr = xin + (size_t)(r0 + row) * 128;
    v0a[rr] = xr[lane];
    v1a[rr] = xr[lane + 64];
  }
  #pragma unroll
  for (int rr = 0; rr < 16; ++rr) {
    int row = wv * 16 + rr;
    float v0 = v0a[rr], v1 = v1a[rr];
    float s = v0 + v1, s2 = v0 * v0 + v1 * v1;
    #pragma unroll
    for (int off = 32; off > 0; off >>= 1) {
      s  += __shfl_xor(s,  off);
      s2 += __shfl_xor(s2, off);
    }
    float mu = s * (1.f / 128.f);
    float var = s2 * (1.f / 128.f) - mu * mu;
    float rs = rsqrtf(var + 1e-5f);
    float y0 = (v0 - mu) * rs * gamma[lane]      + beta[lane];
    float y1 = (v1 - mu) * rs * gamma[lane + 64] + beta[lane + 64];
    int f = (row & 15) >> 1;
    int ca = lane, cb = lane + 64;
    xn[row * 128 + (((ca >> 3) ^ f) << 3) + (ca & 7)] = (short)f2b(y0);
    xn[row * 128 + (((cb >> 3) ^ f) << 3) + (cb & 7)] = (short)f2b(y1);
  }
  __syncthreads();

  mlp_fc1(xn, hb[0], w1t, b1, 0, wv, c, g);
  __syncthreads();

  f32x4 acc2[4][2] = {};
  #pragma unroll
  for (int s = 0; s < 4; ++s) {
    if (s < 3) mlp_fc1(xn, hb[(s + 1) & 1], w1t, b1, s + 1, wv, c, g);
    mlp_fc2(hb[s & 1], w2t, acc2, s, wv, c, g);
    if (s < 3) __syncthreads();
  }

  #pragma unroll
  for (int mi = 0; mi < 4; ++mi) {
    #pragma unroll
    for (int r = 0; r < 4; ++r) {
      int row = r0 + mi * 16 + g * 4 + r;
      #pragma unroll
      for (int ni = 0; ni < 2; ++ni) {
        int col = wv * 32 + ni * 16 + c;
        size_t o = (size_t)row * 128 + col;
        outp[o] = acc2[mi][ni][r] + b2[col] + xin[o];
      }
    }
  }
}

// ---------------------------------------------------------------------------
// Launch
// ---------------------------------------------------------------------------
extern "C" void kernel_launch(void* const* d_in, const int* in_sizes, int n_in,
                              void* d_out, int out_size, void* d_ws, size_t ws_size,
                              hipStream_t stream) {
  const float* x      = (const float*)d_in[0];
  const float* n1g    = (const float*)d_in[1];
  const float* n1b    = (const float*)d_in[2];
  const float* qkv_w  = (const float*)d_in[3];
  const float* qkv_b  = (const float*)d_in[4];
  const float* proj_w = (const float*)d_in[5];
  const float* proj_b = (const float*)d_in[6];
  const float* rpb    = (const float*)d_in[7];
  const float* n2g    = (const float*)d_in[8];
  const float* n2b    = (const float*)d_in[9];
  const float* fc1w   = (const float*)d_in[10];
  const float* fc1b   = (const float*)d_in[11];
  const float* fc2w   = (const float*)d_in[12];
  const float* fc2b   = (const float*)d_in[13];
  float* out = (float*)d_out;
  char* ws = (char*)d_ws;

  __hip_bfloat16* wbuf = (__hip_bfloat16*)ws;
  __hip_bfloat16* w_qkv = wbuf;                 // [384][128]
  __hip_bfloat16* w_prj = wbuf + 49152;         // [128][128]
  __hip_bfloat16* w_fc1 = wbuf + 65536;         // [512][128]
  __hip_bfloat16* w_fc2 = wbuf + 131072;        // [128][512]
  __hip_bfloat16* bias_tab = (__hip_bfloat16*)(ws + 393216);
  float* pbuf = (float*)(ws + 2490368);         // 4096*5*128 f32 = 10.5 MB

  hipLaunchKernelGGL(convert_wt, dim3(192), dim3(256), 0, stream, qkv_w, w_qkv, 128, 384);
  hipLaunchKernelGGL(convert_wt, dim3(64),  dim3(256), 0, stream, proj_w, w_prj, 128, 128);
  hipLaunchKernelGGL(convert_wt, dim3(256), dim3(256), 0, stream, fc1w,  w_fc1, 128, 512);
  hipLaunchKernelGGL(convert_wt, dim3(256), dim3(256), 0, stream, fc2w,  w_fc2, 512, 128);
  hipLaunchKernelGGL(bias_gen, dim3(256), dim3(256), 0, stream, rpb, bias_tab);

  // Phase 1: fully fused (no intermediate HBM traffic)
  hipLaunchKernelGGL(phase1_fused, dim3(4096), dim3(256), 0, stream,
                     x, n1g, n1b, w_qkv, qkv_b, w_prj, proj_b, bias_tab, out, pbuf);
  hipLaunchKernelGGL(prompt_reduce, dim3(320), dim3(128), 0, stream, x, pbuf, out);

  // Phase 2: fused MLP (in-place on out), 201024 = 3141*64 rows
  hipLaunchKernelGGL(mlp_fused, dim3(3141), dim3(256), 0, stream,
                     out, n2g, n2b, w_fc1, fc1b, w_fc2, fc2b, out);
  (void)in_sizes; (void)n_in; (void)out_size; (void)ws_size;
}